// Round 1
// baseline (459.033 us; speedup 1.0000x reference)
//
#include <hip/hip_runtime.h>

#define IN_F   8192
#define OUT_F  8192
#define HALF_F 4096
#define STAGES 13

#define KCHUNK 64    // qweight rows per GEMV block
#define OTILE  1024  // outputs per GEMV block (256 threads x 4)

// ---------------------------------------------------------------------------
// Kernel 1: h = butterfly_V(x / scaleWH), plus sum(h). Single block, 1024 thr.
// Stage semantics (from the reference einsum + interleave):
//   out[m]        =  c*in[2m] + s*in[2m+1]
//   out[n/2 + m]  = -s*in[2m] + c*in[2m+1]
// ---------------------------------------------------------------------------
__global__ __launch_bounds__(1024) void butterfly_in_kernel(
    const float* __restrict__ x, const float* __restrict__ scaleWH,
    const float* __restrict__ V_angles, const int* __restrict__ pin,
    const int* __restrict__ pout, float* __restrict__ h_out,
    float* __restrict__ sum_out)
{
    __shared__ float bufA[IN_F];
    __shared__ float bufB[IN_F];
    const int tid = threadIdx.x;

    // input permutation + reverse diagonal scaling
    for (int j = 0; j < 8; ++j) {
        int k = tid + j * 1024;
        int src = pin[k];
        bufA[k] = x[src] / scaleWH[src];
    }
    __syncthreads();

    float* in = bufA;
    float* out = bufB;
    for (int s = 0; s < STAGES; ++s) {
        const float* ang = V_angles + s * HALF_F;
        for (int j = 0; j < 4; ++j) {
            int m = tid + j * 1024;          // stride-1 writes, stride-2 reads (conflict-free)
            float c, sn;
            sincosf(ang[m], &sn, &c);
            float x0 = in[2 * m];
            float x1 = in[2 * m + 1];
            out[m]          =  c * x0 + sn * x1;
            out[HALF_F + m] = -sn * x0 + c * x1;
        }
        __syncthreads();
        float* t = in; in = out; out = t;
    }

    // output permutation + write h; accumulate block sum
    float local = 0.0f;
    for (int j = 0; j < 8; ++j) {
        int k = tid + j * 1024;
        float v = in[pout[k]];
        h_out[k] = v;
        local += v;
    }
    __syncthreads();
    float* red = out;                         // reuse the spare LDS buffer
    red[tid] = local;
    __syncthreads();
    for (int s = 512; s > 0; s >>= 1) {
        if (tid < s) red[tid] += red[tid + s];
        __syncthreads();
    }
    if (tid == 0) *sum_out = red[0];
}

// ---------------------------------------------------------------------------
// Kernel 2: accum[o] += sum_{i in chunk} q[i][o] * h[i]   (raw int dot; the
// dequant affine correction is applied in kernel 3).
// qweight is (IN_F, OUT_F) row-major: q[i][o] at i*OUT_F + o -> consecutive o
// contiguous. Each thread: 4 outputs via int4 loads (16 B/lane coalesced).
// ---------------------------------------------------------------------------
__global__ __launch_bounds__(256) void gemv_kernel(
    const int* __restrict__ q, const float* __restrict__ h,
    float* __restrict__ accum)
{
    __shared__ float hs[KCHUNK];
    const int tid = threadIdx.x;
    const int ot = blockIdx.x;    // output tile  [0, OUT_F/OTILE)
    const int kc = blockIdx.y;    // k chunk      [0, IN_F/KCHUNK)
    const int i0 = kc * KCHUNK;

    if (tid < KCHUNK) hs[tid] = h[i0 + tid];
    __syncthreads();

    const int o = ot * OTILE + tid * 4;
    const int* qp = q + (size_t)i0 * OUT_F + o;

    float a0 = 0.f, a1 = 0.f, a2 = 0.f, a3 = 0.f;
#pragma unroll 4
    for (int ii = 0; ii < KCHUNK; ++ii) {
        int4 v = *(const int4*)qp;
        qp += OUT_F;
        float hv = hs[ii];
        a0 += hv * (float)v.x;
        a1 += hv * (float)v.y;
        a2 += hv * (float)v.z;
        a3 += hv * (float)v.w;
    }
    atomicAdd(&accum[o + 0], a0);
    atomicAdd(&accum[o + 1], a1);
    atomicAdd(&accum[o + 2], a2);
    atomicAdd(&accum[o + 3], a3);
}

// ---------------------------------------------------------------------------
// Kernel 3: t[o] = scale*((2/15)*accum[o] - sum_h); out = butterfly_U(t)+bias
// ---------------------------------------------------------------------------
__global__ __launch_bounds__(1024) void butterfly_out_kernel(
    const float* __restrict__ accum, const float* __restrict__ sum_h_p,
    const float* __restrict__ scale_p, const float* __restrict__ bias,
    const float* __restrict__ U_angles, const int* __restrict__ pin,
    const int* __restrict__ pout, float* __restrict__ out_f)
{
    __shared__ float bufA[OUT_F];
    __shared__ float bufB[OUT_F];
    const int tid = threadIdx.x;
    const float scale = *scale_p;
    const float sum_h = *sum_h_p;

    for (int j = 0; j < 8; ++j) {
        int k = tid + j * 1024;
        bufA[k] = scale * ((2.0f / 15.0f) * accum[k] - sum_h);
    }
    __syncthreads();
    for (int j = 0; j < 8; ++j) {
        int k = tid + j * 1024;
        bufB[k] = bufA[pin[k]];
    }
    __syncthreads();

    float* in = bufB;
    float* out = bufA;
    for (int s = 0; s < STAGES; ++s) {
        const float* ang = U_angles + s * HALF_F;
        for (int j = 0; j < 4; ++j) {
            int m = tid + j * 1024;
            float c, sn;
            sincosf(ang[m], &sn, &c);
            float x0 = in[2 * m];
            float x1 = in[2 * m + 1];
            out[m]          =  c * x0 + sn * x1;
            out[HALF_F + m] = -sn * x0 + c * x1;
        }
        __syncthreads();
        float* t = in; in = out; out = t;
    }

    for (int j = 0; j < 8; ++j) {
        int k = tid + j * 1024;
        out_f[k] = in[pout[k]] + bias[k];
    }
}

// ---------------------------------------------------------------------------
extern "C" void kernel_launch(void* const* d_in, const int* in_sizes, int n_in,
                              void* d_out, int out_size, void* d_ws, size_t ws_size,
                              hipStream_t stream) {
    const float* x        = (const float*)d_in[0];
    const int*   qweight  = (const int*)  d_in[1];
    const float* scaleWH  = (const float*)d_in[2];
    const float* scale    = (const float*)d_in[3];
    const float* bias     = (const float*)d_in[4];
    const float* U_angles = (const float*)d_in[5];
    const float* V_angles = (const float*)d_in[6];
    const int*   pU_in    = (const int*)  d_in[7];
    const int*   pU_out   = (const int*)  d_in[8];
    const int*   pV_in    = (const int*)  d_in[9];
    const int*   pV_out   = (const int*)  d_in[10];
    float* out = (float*)d_out;

    // ws layout: [0, IN_F) h ; [IN_F, IN_F+OUT_F) accum ; [IN_F+OUT_F] sum_h
    float* h     = (float*)d_ws;
    float* accum = h + IN_F;
    float* sum_h = accum + OUT_F;

    hipMemsetAsync(accum, 0, OUT_F * sizeof(float), stream);

    butterfly_in_kernel<<<1, 1024, 0, stream>>>(
        x, scaleWH, V_angles, pV_in, pV_out, h, sum_h);

    gemv_kernel<<<dim3(OUT_F / OTILE, IN_F / KCHUNK), 256, 0, stream>>>(
        qweight, h, accum);

    butterfly_out_kernel<<<1, 1024, 0, stream>>>(
        accum, sum_h, scale, bias, U_angles, pU_in, pU_out, out);
}

// Round 2
// 412.506 us; speedup vs baseline: 1.1128x; 1.1128x over previous
//
#include <hip/hip_runtime.h>

#define IN_F   8192
#define OUT_F  8192
#define HALF_F 4096
#define STAGES 13

#define KCHUNK 64    // qweight rows per GEMV block
#define OTILE  1024  // outputs per GEMV block (256 threads x 4)

// ---------------------------------------------------------------------------
// Kernel 1: h = butterfly_V(x / scaleWH), plus sum(h); also zeroes accum[]
// (stream order guarantees this completes before the GEMV's atomics).
// Single block, 1024 threads.
// Stage semantics (from the reference einsum + interleave):
//   out[m]        =  c*in[2m] + s*in[2m+1]
//   out[n/2 + m]  = -s*in[2m] + c*in[2m+1]
// __sincosf (hw v_sin/v_cos): angles are in [0,2pi], ~1e-6 error; final
// output error ~1e-2 vs threshold 3.8 (measured 0.0156 with libm sincos).
// ---------------------------------------------------------------------------
__global__ __launch_bounds__(1024) void butterfly_in_kernel(
    const float* __restrict__ x, const float* __restrict__ scaleWH,
    const float* __restrict__ V_angles, const int* __restrict__ pin,
    const int* __restrict__ pout, float* __restrict__ h_out,
    float* __restrict__ sum_out, float* __restrict__ accum)
{
    __shared__ float bufA[IN_F];
    __shared__ float bufB[IN_F];
    const int tid = threadIdx.x;

    // zero the GEMV accumulator (replaces a separate hipMemsetAsync dispatch)
#pragma unroll
    for (int j = 0; j < 8; ++j) accum[tid + j * 1024] = 0.0f;

    // input permutation + reverse diagonal scaling
#pragma unroll
    for (int j = 0; j < 8; ++j) {
        int k = tid + j * 1024;
        int src = pin[k];
        bufA[k] = x[src] / scaleWH[src];
    }
    __syncthreads();

    float* in = bufA;
    float* out = bufB;
    for (int s = 0; s < STAGES; ++s) {
        const float* ang = V_angles + s * HALF_F;
#pragma unroll
        for (int j = 0; j < 4; ++j) {
            int m = tid + j * 1024;          // stride-1 writes, stride-2 reads
            float c, sn;
            __sincosf(ang[m], &sn, &c);
            float x0 = in[2 * m];
            float x1 = in[2 * m + 1];
            out[m]          =  c * x0 + sn * x1;
            out[HALF_F + m] = -sn * x0 + c * x1;
        }
        __syncthreads();
        float* t = in; in = out; out = t;
    }

    // output permutation + write h; accumulate block sum
    float local = 0.0f;
#pragma unroll
    for (int j = 0; j < 8; ++j) {
        int k = tid + j * 1024;
        float v = in[pout[k]];
        h_out[k] = v;
        local += v;
    }
    __syncthreads();
    float* red = out;                         // reuse the spare LDS buffer
    red[tid] = local;
    __syncthreads();
    for (int s = 512; s > 0; s >>= 1) {
        if (tid < s) red[tid] += red[tid + s];
        __syncthreads();
    }
    if (tid == 0) *sum_out = red[0];
}

// ---------------------------------------------------------------------------
// Kernel 2: accum[o] += sum_{i in chunk} q[i][o] * h[i]   (raw int dot; the
// dequant affine correction is applied in kernel 3).
// qweight is (IN_F, OUT_F) row-major: q[i][o] at i*OUT_F + o -> consecutive o
// contiguous. Each thread: 4 outputs via int4 loads (16 B/lane coalesced).
// ---------------------------------------------------------------------------
__global__ __launch_bounds__(256) void gemv_kernel(
    const int* __restrict__ q, const float* __restrict__ h,
    float* __restrict__ accum)
{
    __shared__ float hs[KCHUNK];
    const int tid = threadIdx.x;
    const int ot = blockIdx.x;    // output tile  [0, OUT_F/OTILE)
    const int kc = blockIdx.y;    // k chunk      [0, IN_F/KCHUNK)
    const int i0 = kc * KCHUNK;

    if (tid < KCHUNK) hs[tid] = h[i0 + tid];
    __syncthreads();

    const int o = ot * OTILE + tid * 4;
    const int* qp = q + (size_t)i0 * OUT_F + o;

    float a0 = 0.f, a1 = 0.f, a2 = 0.f, a3 = 0.f;
#pragma unroll 4
    for (int ii = 0; ii < KCHUNK; ++ii) {
        int4 v = *(const int4*)qp;
        qp += OUT_F;
        float hv = hs[ii];
        a0 += hv * (float)v.x;
        a1 += hv * (float)v.y;
        a2 += hv * (float)v.z;
        a3 += hv * (float)v.w;
    }
    atomicAdd(&accum[o + 0], a0);
    atomicAdd(&accum[o + 1], a1);
    atomicAdd(&accum[o + 2], a2);
    atomicAdd(&accum[o + 3], a3);
}

// ---------------------------------------------------------------------------
// Kernel 3: t[o] = scale*((2/15)*accum[o] - sum_h); out = butterfly_U(t)+bias
// ---------------------------------------------------------------------------
__global__ __launch_bounds__(1024) void butterfly_out_kernel(
    const float* __restrict__ accum, const float* __restrict__ sum_h_p,
    const float* __restrict__ scale_p, const float* __restrict__ bias,
    const float* __restrict__ U_angles, const int* __restrict__ pin,
    const int* __restrict__ pout, float* __restrict__ out_f)
{
    __shared__ float bufA[OUT_F];
    __shared__ float bufB[OUT_F];
    const int tid = threadIdx.x;
    const float scale = *scale_p;
    const float sum_h = *sum_h_p;

#pragma unroll
    for (int j = 0; j < 8; ++j) {
        int k = tid + j * 1024;
        bufA[k] = scale * ((2.0f / 15.0f) * accum[k] - sum_h);
    }
    __syncthreads();
#pragma unroll
    for (int j = 0; j < 8; ++j) {
        int k = tid + j * 1024;
        bufB[k] = bufA[pin[k]];
    }
    __syncthreads();

    float* in = bufB;
    float* out = bufA;
    for (int s = 0; s < STAGES; ++s) {
        const float* ang = U_angles + s * HALF_F;
#pragma unroll
        for (int j = 0; j < 4; ++j) {
            int m = tid + j * 1024;
            float c, sn;
            __sincosf(ang[m], &sn, &c);
            float x0 = in[2 * m];
            float x1 = in[2 * m + 1];
            out[m]          =  c * x0 + sn * x1;
            out[HALF_F + m] = -sn * x0 + c * x1;
        }
        __syncthreads();
        float* t = in; in = out; out = t;
    }

#pragma unroll
    for (int j = 0; j < 8; ++j) {
        int k = tid + j * 1024;
        out_f[k] = in[pout[k]] + bias[k];
    }
}

// ---------------------------------------------------------------------------
extern "C" void kernel_launch(void* const* d_in, const int* in_sizes, int n_in,
                              void* d_out, int out_size, void* d_ws, size_t ws_size,
                              hipStream_t stream) {
    const float* x        = (const float*)d_in[0];
    const int*   qweight  = (const int*)  d_in[1];
    const float* scaleWH  = (const float*)d_in[2];
    const float* scale    = (const float*)d_in[3];
    const float* bias     = (const float*)d_in[4];
    const float* U_angles = (const float*)d_in[5];
    const float* V_angles = (const float*)d_in[6];
    const int*   pU_in    = (const int*)  d_in[7];
    const int*   pU_out   = (const int*)  d_in[8];
    const int*   pV_in    = (const int*)  d_in[9];
    const int*   pV_out   = (const int*)  d_in[10];
    float* out = (float*)d_out;

    // ws layout: [0, IN_F) h ; [IN_F, IN_F+OUT_F) accum ; [IN_F+OUT_F] sum_h
    float* h     = (float*)d_ws;
    float* accum = h + IN_F;
    float* sum_h = accum + OUT_F;

    butterfly_in_kernel<<<1, 1024, 0, stream>>>(
        x, scaleWH, V_angles, pV_in, pV_out, h, sum_h, accum);

    gemv_kernel<<<dim3(OUT_F / OTILE, IN_F / KCHUNK), 256, 0, stream>>>(
        qweight, h, accum);

    butterfly_out_kernel<<<1, 1024, 0, stream>>>(
        accum, sum_h, scale, bias, U_angles, pU_in, pU_out, out);
}

// Round 4
// 396.235 us; speedup vs baseline: 1.1585x; 1.0411x over previous
//
#include <hip/hip_runtime.h>

#define IN_F   8192
#define OUT_F  8192
#define HALF_F 4096
#define STAGES 13

#define KCHUNK 64               // qweight rows per GEMV block
#define NCHUNK (IN_F / KCHUNK)  // 128 k-chunks
#define OTILE  1024             // outputs per GEMV block (256 threads x 4)

// clang-native vector types (HIP's int4/float4 are structs, which
// __builtin_nontemporal_load rejects)
typedef int   v4i __attribute__((ext_vector_type(4)));
typedef float v4f __attribute__((ext_vector_type(4)));

// ---------------------------------------------------------------------------
// Kernel 1: h = butterfly_V(x / scaleWH), plus sum(h). Single block, 1024 thr.
// Stage semantics (reference einsum + interleave):
//   out[m]        =  c*in[2m] + s*in[2m+1]
//   out[n/2 + m]  = -s*in[2m] + c*in[2m+1]
// __sincosf (hw v_sin/v_cos): angles in [0,2pi]; measured absmax 0.0625 vs
// threshold 3.8.
// ---------------------------------------------------------------------------
__global__ __launch_bounds__(1024) void butterfly_in_kernel(
    const float* __restrict__ x, const float* __restrict__ scaleWH,
    const float* __restrict__ V_angles, const int* __restrict__ pin,
    const int* __restrict__ pout, float* __restrict__ h_out,
    float* __restrict__ sum_out)
{
    __shared__ float bufA[IN_F];
    __shared__ float bufB[IN_F];
    const int tid = threadIdx.x;

#pragma unroll
    for (int j = 0; j < 8; ++j) {
        int k = tid + j * 1024;
        int src = pin[k];
        bufA[k] = x[src] / scaleWH[src];
    }
    __syncthreads();

    float* in = bufA;
    float* out = bufB;
    for (int s = 0; s < STAGES; ++s) {
        const float* ang = V_angles + s * HALF_F;
#pragma unroll
        for (int j = 0; j < 4; ++j) {
            int m = tid + j * 1024;          // stride-1 writes, stride-2 reads
            float c, sn;
            __sincosf(ang[m], &sn, &c);
            float x0 = in[2 * m];
            float x1 = in[2 * m + 1];
            out[m]          =  c * x0 + sn * x1;
            out[HALF_F + m] = -sn * x0 + c * x1;
        }
        __syncthreads();
        float* t = in; in = out; out = t;
    }

    float local = 0.0f;
#pragma unroll
    for (int j = 0; j < 8; ++j) {
        int k = tid + j * 1024;
        float v = in[pout[k]];
        h_out[k] = v;
        local += v;
    }
    __syncthreads();
    float* red = out;                         // reuse the spare LDS buffer
    red[tid] = local;
    __syncthreads();
    for (int s = 512; s > 0; s >>= 1) {
        if (tid < s) red[tid] += red[tid + s];
        __syncthreads();
    }
    if (tid == 0) *sum_out = red[0];
}

// ---------------------------------------------------------------------------
// Kernel 2: partials[kc][o] = sum_{i in chunk kc} q[i][o] * h[i]
// NO atomics: each (kc, o) cell written exactly once, coalesced. The R2
// version's 1M fp32 atomicAdds onto 512 cachelines serialized at L2;
// this writes 4 MiB of partials instead.
// qweight (IN_F, OUT_F) row-major; v4i loads = 16 B/lane coalesced,
// nontemporal (256 MiB pure stream — keep it out of L2).
// ---------------------------------------------------------------------------
__global__ __launch_bounds__(256) void gemv_kernel(
    const int* __restrict__ q, const float* __restrict__ h,
    float* __restrict__ partials)
{
    __shared__ float hs[KCHUNK];
    const int tid = threadIdx.x;
    const int ot = blockIdx.x;    // output tile  [0, OUT_F/OTILE)
    const int kc = blockIdx.y;    // k chunk      [0, NCHUNK)
    const int i0 = kc * KCHUNK;

    if (tid < KCHUNK) hs[tid] = h[i0 + tid];
    __syncthreads();

    const int o = ot * OTILE + tid * 4;
    const int* qp = q + (size_t)i0 * OUT_F + o;

    float a0 = 0.f, a1 = 0.f, a2 = 0.f, a3 = 0.f;
#pragma unroll 4
    for (int ii = 0; ii < KCHUNK; ++ii) {
        v4i v = __builtin_nontemporal_load((const v4i*)qp);
        qp += OUT_F;
        float hv = hs[ii];
        a0 += hv * (float)v[0];
        a1 += hv * (float)v[1];
        a2 += hv * (float)v[2];
        a3 += hv * (float)v[3];
    }
    v4f r; r[0] = a0; r[1] = a1; r[2] = a2; r[3] = a3;
    *(v4f*)(partials + (size_t)kc * OUT_F + o) = r;
}

// ---------------------------------------------------------------------------
// Kernel 2b: accum[o] = sum_kc partials[kc][o].  32 blocks x 256 threads,
// lane-consecutive o -> fully coalesced reads of the 4 MiB partial matrix.
// ---------------------------------------------------------------------------
__global__ __launch_bounds__(256) void reduce_kernel(
    const float* __restrict__ partials, float* __restrict__ accum)
{
    const int o = blockIdx.x * 256 + threadIdx.x;
    float s = 0.0f;
#pragma unroll 8
    for (int c = 0; c < NCHUNK; ++c) s += partials[(size_t)c * OUT_F + o];
    accum[o] = s;
}

// ---------------------------------------------------------------------------
// Kernel 3: t[o] = scale*((2/15)*accum[o] - sum_h); out = butterfly_U(t)+bias
// ---------------------------------------------------------------------------
__global__ __launch_bounds__(1024) void butterfly_out_kernel(
    const float* __restrict__ accum, const float* __restrict__ sum_h_p,
    const float* __restrict__ scale_p, const float* __restrict__ bias,
    const float* __restrict__ U_angles, const int* __restrict__ pin,
    const int* __restrict__ pout, float* __restrict__ out_f)
{
    __shared__ float bufA[OUT_F];
    __shared__ float bufB[OUT_F];
    const int tid = threadIdx.x;
    const float scale = *scale_p;
    const float sum_h = *sum_h_p;

#pragma unroll
    for (int j = 0; j < 8; ++j) {
        int k = tid + j * 1024;
        bufA[k] = scale * ((2.0f / 15.0f) * accum[k] - sum_h);
    }
    __syncthreads();
#pragma unroll
    for (int j = 0; j < 8; ++j) {
        int k = tid + j * 1024;
        bufB[k] = bufA[pin[k]];
    }
    __syncthreads();

    float* in = bufB;
    float* out = bufA;
    for (int s = 0; s < STAGES; ++s) {
        const float* ang = U_angles + s * HALF_F;
#pragma unroll
        for (int j = 0; j < 4; ++j) {
            int m = tid + j * 1024;
            float c, sn;
            __sincosf(ang[m], &sn, &c);
            float x0 = in[2 * m];
            float x1 = in[2 * m + 1];
            out[m]          =  c * x0 + sn * x1;
            out[HALF_F + m] = -sn * x0 + c * x1;
        }
        __syncthreads();
        float* t = in; in = out; out = t;
    }

#pragma unroll
    for (int j = 0; j < 8; ++j) {
        int k = tid + j * 1024;
        out_f[k] = in[pout[k]] + bias[k];
    }
}

// ---------------------------------------------------------------------------
extern "C" void kernel_launch(void* const* d_in, const int* in_sizes, int n_in,
                              void* d_out, int out_size, void* d_ws, size_t ws_size,
                              hipStream_t stream) {
    const float* x        = (const float*)d_in[0];
    const int*   qweight  = (const int*)  d_in[1];
    const float* scaleWH  = (const float*)d_in[2];
    const float* scale    = (const float*)d_in[3];
    const float* bias     = (const float*)d_in[4];
    const float* U_angles = (const float*)d_in[5];
    const float* V_angles = (const float*)d_in[6];
    const int*   pU_in    = (const int*)  d_in[7];
    const int*   pU_out   = (const int*)  d_in[8];
    const int*   pV_in    = (const int*)  d_in[9];
    const int*   pV_out   = (const int*)  d_in[10];
    float* out = (float*)d_out;

    // ws layout: h[8192] | sum_h[1]+pad[7] | accum[8192] | partials[128*8192]
    float* h        = (float*)d_ws;
    float* sum_h    = h + IN_F;
    float* accum    = sum_h + 8;
    float* partials = accum + OUT_F;

    butterfly_in_kernel<<<1, 1024, 0, stream>>>(
        x, scaleWH, V_angles, pV_in, pV_out, h, sum_h);

    gemv_kernel<<<dim3(OUT_F / OTILE, NCHUNK), 256, 0, stream>>>(
        qweight, h, partials);

    reduce_kernel<<<OUT_F / 256, 256, 0, stream>>>(partials, accum);

    butterfly_out_kernel<<<1, 1024, 0, stream>>>(
        accum, sum_h, scale, bias, U_angles, pU_in, pU_out, out);
}

// Round 5
// 395.031 us; speedup vs baseline: 1.1620x; 1.0030x over previous
//
#include <hip/hip_runtime.h>

#define IN_F   8192
#define OUT_F  8192
#define HALF_F 4096
#define STAGES 13

#define KCHUNK 64               // qweight rows per GEMV block
#define NCHUNK (IN_F / KCHUNK)  // 128 k-chunks
#define OTILE  1024             // outputs per GEMV block (256 threads x 4)

// clang-native vector types (HIP's int4/float4 are structs, which
// __builtin_nontemporal_load rejects)
typedef int   v4i __attribute__((ext_vector_type(4)));
typedef float v4f __attribute__((ext_vector_type(4)));

// ---------------------------------------------------------------------------
// Kernel 1 (14 blocks x 1024):
//   block 0     : h = butterfly_V(x / scaleWH) + sum(h)   (single-CU critical path)
//   blocks 1..13: precompute U-stage cos/sin tables into ws (overlapped on
//                 other CUs; consumed by butterfly_out one dispatch later —
//                 no intra-dispatch communication, so no coherence hazard)
// Stage semantics (reference einsum + interleave):
//   out[m]        =  c*in[2m] + s*in[2m+1]
//   out[n/2 + m]  = -s*in[2m] + c*in[2m+1]
// __sincosf (hw v_sin/v_cos): angles in [0,2pi]; measured absmax 0.0156 vs
// threshold 3.8.
// ---------------------------------------------------------------------------
__global__ __launch_bounds__(1024) void butterfly_in_kernel(
    const float* __restrict__ x, const float* __restrict__ scaleWH,
    const float* __restrict__ V_angles, const float* __restrict__ U_angles,
    const int* __restrict__ pin, const int* __restrict__ pout,
    float* __restrict__ h_out, float* __restrict__ sum_out,
    float2* __restrict__ u_tab)
{
    const int tid = threadIdx.x;

    if (blockIdx.x != 0) {
        // ---- U table producer: stage s = blockIdx.x - 1 ----
        const int s = blockIdx.x - 1;
        const float* ang = U_angles + s * HALF_F;
#pragma unroll
        for (int j = 0; j < 4; ++j) {
            int m = tid + j * 1024;
            float c, sn;
            __sincosf(ang[m], &sn, &c);
            u_tab[s * HALF_F + m] = make_float2(c, sn);
        }
        return;
    }

    // ---- block 0: V butterfly ----
    __shared__ float bufA[IN_F];
    __shared__ float bufB[IN_F];

#pragma unroll
    for (int j = 0; j < 8; ++j) {
        int k = tid + j * 1024;
        int src = pin[k];
        bufA[k] = x[src] / scaleWH[src];
    }
    __syncthreads();

    float* in = bufA;
    float* out = bufB;
    for (int s = 0; s < STAGES; ++s) {
        const float* ang = V_angles + s * HALF_F;
#pragma unroll
        for (int j = 0; j < 4; ++j) {
            int m = tid + j * 1024;          // stride-1 writes, stride-2 reads
            float c, sn;
            __sincosf(ang[m], &sn, &c);
            float x0 = in[2 * m];
            float x1 = in[2 * m + 1];
            out[m]          =  c * x0 + sn * x1;
            out[HALF_F + m] = -sn * x0 + c * x1;
        }
        __syncthreads();
        float* t = in; in = out; out = t;
    }

    float local = 0.0f;
#pragma unroll
    for (int j = 0; j < 8; ++j) {
        int k = tid + j * 1024;
        float v = in[pout[k]];
        h_out[k] = v;
        local += v;
    }
    __syncthreads();
    float* red = out;                         // reuse the spare LDS buffer
    red[tid] = local;
    __syncthreads();
    for (int s = 512; s > 0; s >>= 1) {
        if (tid < s) red[tid] += red[tid + s];
        __syncthreads();
    }
    if (tid == 0) *sum_out = red[0];
}

// ---------------------------------------------------------------------------
// Kernel 2: partials[kc][o] = sum_{i in chunk kc} q[i][o] * h[i]
// No atomics; each (kc,o) cell written once, coalesced. qweight (IN_F,OUT_F)
// row-major; v4i nontemporal loads = 16 B/lane coalesced (256 MiB pure
// stream — keep it out of L2). Memory-bound: floor ~40 us at 6.7 TB/s.
// ---------------------------------------------------------------------------
__global__ __launch_bounds__(256) void gemv_kernel(
    const int* __restrict__ q, const float* __restrict__ h,
    float* __restrict__ partials)
{
    __shared__ float hs[KCHUNK];
    const int tid = threadIdx.x;
    const int ot = blockIdx.x;    // output tile  [0, OUT_F/OTILE)
    const int kc = blockIdx.y;    // k chunk      [0, NCHUNK)
    const int i0 = kc * KCHUNK;

    if (tid < KCHUNK) hs[tid] = h[i0 + tid];
    __syncthreads();

    const int o = ot * OTILE + tid * 4;
    const int* qp = q + (size_t)i0 * OUT_F + o;

    float a0 = 0.f, a1 = 0.f, a2 = 0.f, a3 = 0.f;
#pragma unroll 4
    for (int ii = 0; ii < KCHUNK; ++ii) {
        v4i v = __builtin_nontemporal_load((const v4i*)qp);
        qp += OUT_F;
        float hv = hs[ii];
        a0 += hv * (float)v[0];
        a1 += hv * (float)v[1];
        a2 += hv * (float)v[2];
        a3 += hv * (float)v[3];
    }
    v4f r; r[0] = a0; r[1] = a1; r[2] = a2; r[3] = a3;
    *(v4f*)(partials + (size_t)kc * OUT_F + o) = r;
}

// ---------------------------------------------------------------------------
// Kernel 2b: accum[o] = sum_kc partials[kc][o].  32 blocks x 256 threads,
// lane-consecutive o -> fully coalesced reads of the 4 MiB partial matrix.
// ---------------------------------------------------------------------------
__global__ __launch_bounds__(256) void reduce_kernel(
    const float* __restrict__ partials, float* __restrict__ accum)
{
    const int o = blockIdx.x * 256 + threadIdx.x;
    float s = 0.0f;
#pragma unroll 8
    for (int c = 0; c < NCHUNK; ++c) s += partials[(size_t)c * OUT_F + o];
    accum[o] = s;
}

// ---------------------------------------------------------------------------
// Kernel 3: t[o] = scale*((2/15)*accum[o] - sum_h); out = butterfly_U(t)+bias
// Reads precomputed cos/sin tables (written by kernel 1's producer blocks)
// instead of computing 52 __sincosf per thread on the single-CU path.
// ---------------------------------------------------------------------------
__global__ __launch_bounds__(1024) void butterfly_out_kernel(
    const float* __restrict__ accum, const float* __restrict__ sum_h_p,
    const float* __restrict__ scale_p, const float* __restrict__ bias,
    const float2* __restrict__ u_tab, const int* __restrict__ pin,
    const int* __restrict__ pout, float* __restrict__ out_f)
{
    __shared__ float bufA[OUT_F];
    __shared__ float bufB[OUT_F];
    const int tid = threadIdx.x;
    const float scale = *scale_p;
    const float sum_h = *sum_h_p;

#pragma unroll
    for (int j = 0; j < 8; ++j) {
        int k = tid + j * 1024;
        bufA[k] = scale * ((2.0f / 15.0f) * accum[k] - sum_h);
    }
    __syncthreads();
#pragma unroll
    for (int j = 0; j < 8; ++j) {
        int k = tid + j * 1024;
        bufB[k] = bufA[pin[k]];
    }
    __syncthreads();

    float* in = bufB;
    float* out = bufA;
    for (int s = 0; s < STAGES; ++s) {
        const float2* tab = u_tab + s * HALF_F;
#pragma unroll
        for (int j = 0; j < 4; ++j) {
            int m = tid + j * 1024;
            float2 cs = tab[m];               // coalesced 8 B/lane, L2/L3-hot
            float x0 = in[2 * m];
            float x1 = in[2 * m + 1];
            out[m]          =  cs.x * x0 + cs.y * x1;
            out[HALF_F + m] = -cs.y * x0 + cs.x * x1;
        }
        __syncthreads();
        float* t = in; in = out; out = t;
    }

#pragma unroll
    for (int j = 0; j < 8; ++j) {
        int k = tid + j * 1024;
        out_f[k] = in[pout[k]] + bias[k];
    }
}

// ---------------------------------------------------------------------------
extern "C" void kernel_launch(void* const* d_in, const int* in_sizes, int n_in,
                              void* d_out, int out_size, void* d_ws, size_t ws_size,
                              hipStream_t stream) {
    const float* x        = (const float*)d_in[0];
    const int*   qweight  = (const int*)  d_in[1];
    const float* scaleWH  = (const float*)d_in[2];
    const float* scale    = (const float*)d_in[3];
    const float* bias     = (const float*)d_in[4];
    const float* U_angles = (const float*)d_in[5];
    const float* V_angles = (const float*)d_in[6];
    const int*   pU_in    = (const int*)  d_in[7];
    const int*   pU_out   = (const int*)  d_in[8];
    const int*   pV_in    = (const int*)  d_in[9];
    const int*   pV_out   = (const int*)  d_in[10];
    float* out = (float*)d_out;

    // ws layout: h[8192] | sum_h[8] | accum[8192] | u_tab[13*4096 float2]
    //            | partials[128*8192]
    float*  h        = (float*)d_ws;
    float*  sum_h    = h + IN_F;
    float*  accum    = sum_h + 8;
    float2* u_tab    = (float2*)(accum + OUT_F);
    float*  partials = (float*)(u_tab + STAGES * HALF_F);

    butterfly_in_kernel<<<1 + STAGES, 1024, 0, stream>>>(
        x, scaleWH, V_angles, U_angles, pV_in, pV_out, h, sum_h, u_tab);

    gemv_kernel<<<dim3(OUT_F / OTILE, NCHUNK), 256, 0, stream>>>(
        qweight, h, partials);

    reduce_kernel<<<OUT_F / 256, 256, 0, stream>>>(partials, accum);

    butterfly_out_kernel<<<1, 1024, 0, stream>>>(
        accum, sum_h, scale, bias, u_tab, pU_in, pU_out, out);
}